// Round 10
// baseline (177.633 us; speedup 1.0000x reference)
//
#include <hip/hip_runtime.h>
#include <hip/hip_bf16.h>
#include <cstdint>
#include <cstddef>

#define B_  2
#define N_  2048
#define D_  1024
#define H_  16
#define DH_ 64
#define E3_ 192   // 3*DH

typedef __attribute__((ext_vector_type(8))) short short8;
typedef __attribute__((ext_vector_type(8))) unsigned short ushort8v;
typedef __attribute__((ext_vector_type(4))) float floatx4;

static __device__ __forceinline__ unsigned short f2bf(float f) {
  union { float f; unsigned u; } c; c.f = f;
  unsigned r = c.u + 0x7fffu + ((c.u >> 16) & 1u);   // RNE
  return (unsigned short)(r >> 16);
}

#define MFMA(a,b,c) __builtin_amdgcn_mfma_f32_16x16x32_bf16((a),(b),(c),0,0,0)

// async global->LDS, 16B per lane, dest = uniform base + lane*16
#define GL_LDS16(g, l) __builtin_amdgcn_global_load_lds( \
    (const __attribute__((address_space(1))) void*)(g),  \
    (__attribute__((address_space(3))) void*)(l), 16, 0, 0)

// ---------------- merged prep: x->bf16 | W_kqv transpose | Wproj->bf16 ------
// grid = 2048 (x) + 768 (twkqv) + 512 (Wproj)
__global__ __launch_bounds__(256) void k_prep(const float* __restrict__ x,
                                              const float* __restrict__ Wkqv,
                                              const float* __restrict__ Wproj,
                                              unsigned short* __restrict__ Xb,
                                              unsigned short* __restrict__ Wt,
                                              unsigned short* __restrict__ Wpb) {
  __shared__ float tile[64][65];
  int bx = blockIdx.x, t = threadIdx.x;
  if (bx < 2048 || bx >= 2816) {            // plain f2bf converts
    const float* in = (bx < 2048) ? x : Wproj;
    unsigned short* out = (bx < 2048) ? Xb : Wpb;
    int i = ((bx < 2048) ? bx : bx - 2816) * 256 + t;
    const float4* p = (const float4*)in + (size_t)i * 2;
    float4 a = p[0], b = p[1];
    ushort8v o;
    o[0]=f2bf(a.x); o[1]=f2bf(a.y); o[2]=f2bf(a.z); o[3]=f2bf(a.w);
    o[4]=f2bf(b.x); o[5]=f2bf(b.y); o[6]=f2bf(b.z); o[7]=f2bf(b.w);
    *((ushort8v*)out + i) = o;
    return;
  }
  // W_kqv [h][d][e] -> Wt [cat][h][e'][d]  (col' = cat*1024 + h*64 + e')
  int idx = bx - 2048;
  int d0 = (idx & 15) * 64, rem = idx >> 4;
  int cat = rem % 3, h = rem / 3, e0 = cat * 64;
  const float* Wp = Wkqv + (size_t)h * D_ * E3_;
  int dr = t >> 2, ec = (t & 3) * 16;
#pragma unroll
  for (int j = 0; j < 16; j += 4) {
    float4 wv = *(const float4*)&Wp[(size_t)(d0 + dr) * E3_ + e0 + ec + j];
    tile[dr][ec + j + 0] = wv.x; tile[dr][ec + j + 1] = wv.y;
    tile[dr][ec + j + 2] = wv.z; tile[dr][ec + j + 3] = wv.w;
  }
  __syncthreads();
  int er = t >> 2, dc = (t & 3) * 16;
  ushort8v o0, o1;
#pragma unroll
  for (int j = 0; j < 8; j++) o0[j] = f2bf(tile[dc + j][er]);
#pragma unroll
  for (int j = 0; j < 8; j++) o1[j] = f2bf(tile[dc + 8 + j][er]);
  size_t o = ((size_t)(cat * 1024 + h * 64 + er)) * D_ + d0 + dc;
  *(ushort8v*)&Wt[o]     = o0;
  *(ushort8v*)&Wt[o + 8] = o1;
}

// ------------- QKV GEMM: 256x256 tile, BK=64, 8-wave, 4-phase/K-step --------
// m201-style schedule; counted vmcnt(2) once per K-step; chunk^(row&7) LDS
// swizzle via pre-swizzled global source. Q output pre-scaled by 0.125*log2e
// so k_flash can use exp2 directly (softmax in log2 domain).
__global__ __launch_bounds__(512, 2) void k_qkv(const unsigned short* __restrict__ Xb,
                                                const unsigned short* __restrict__ Wt,
                                                const float* __restrict__ bkqv,
                                                unsigned short* __restrict__ Qb,
                                                unsigned short* __restrict__ Kb,
                                                unsigned short* __restrict__ Vt) {
  __shared__ unsigned short LDSf[65536];   // 128 KiB: A[2][256][64] | B[2][256][64]
  const int t = threadIdx.x;
  const int wid = t >> 6, lane = t & 63, quad = lane >> 4, l16 = lane & 15;
  const int wr = wid >> 2, wc = wid & 3;
  const int m0 = blockIdx.x * 256, c0 = blockIdx.y * 256;

  floatx4 acc[8][4];
#pragma unroll
  for (int i = 0; i < 8; i++)
#pragma unroll
    for (int j = 0; j < 4; j++) acc[i][j] = (floatx4){0.f, 0.f, 0.f, 0.f};

  // staging: thread t covers quarter-local row t>>3, swizzled chunk (t&7)^(row&7)
  const int slr = t >> 3;
  const int sco = ((t & 7) ^ (slr & 7)) * 8;
  const unsigned short* gA0 = Xb + (size_t)(m0 +   0 + slr) * D_ + sco;
  const unsigned short* gA1 = Xb + (size_t)(m0 +  64 + slr) * D_ + sco;
  const unsigned short* gA2 = Xb + (size_t)(m0 + 128 + slr) * D_ + sco;
  const unsigned short* gA3 = Xb + (size_t)(m0 + 192 + slr) * D_ + sco;
  const unsigned short* gB0 = Wt + (size_t)(c0 +   0 + slr) * D_ + sco;
  const unsigned short* gB1 = Wt + (size_t)(c0 +  64 + slr) * D_ + sco;
  const unsigned short* gB2 = Wt + (size_t)(c0 + 128 + slr) * D_ + sco;
  const unsigned short* gB3 = Wt + (size_t)(c0 + 192 + slr) * D_ + sco;
#define SA(gp, q, s, bb) GL_LDS16((gp) + (s) * 64, &LDSf[(bb) * 16384 + (q) * 4096 + t * 8])
#define SB(gp, q, s, bb) GL_LDS16((gp) + (s) * 64, &LDSf[32768 + (bb) * 16384 + (q) * 4096 + t * 8])

  // frag read addressing: chunk (4*ks+quad) ^ (l16&7), row stride 64 ushort
  const int aoff0 = ((quad)     ^ (l16 & 7)) * 8;
  const int aoff1 = ((4 + quad) ^ (l16 & 7)) * 8;
  const unsigned short* Abase = &LDSf[(wr * 128 + l16) * 64];
  const unsigned short* Bbase = &LDSf[32768 + (wc * 64 + l16) * 64];

  // prologue: step0 full (8) + A(1)q0,q2 (2); retire to 2 -> step0 ready
  SA(gA0, 0, 0, 0); SA(gA1, 1, 0, 0); SA(gA2, 2, 0, 0); SA(gA3, 3, 0, 0);
  SB(gB0, 0, 0, 0); SB(gB1, 1, 0, 0); SB(gB2, 2, 0, 0); SB(gB3, 3, 0, 0);
  SA(gA0, 0, 1, 1); SA(gA2, 2, 1, 1);
  asm volatile("s_waitcnt vmcnt(2)" ::: "memory");
  __builtin_amdgcn_s_barrier();

  for (int s = 0; s < 16; s++) {
    const int buf = s & 1, nbuf = buf ^ 1;
    const int so = buf * 16384;
    short8 a[4][2], b[4][2];
    // -------- p0: read A(mh0)+B(nh0); stage A(s+1)q1,q3 + B(s+1)q0-3 -------
#pragma unroll
    for (int mi = 0; mi < 4; mi++) {
      a[mi][0] = *(const short8*)&Abase[so + mi * 1024 + aoff0];
      a[mi][1] = *(const short8*)&Abase[so + mi * 1024 + aoff1];
    }
#pragma unroll
    for (int ni = 0; ni < 2; ni++) {
      b[ni][0] = *(const short8*)&Bbase[so + ni * 1024 + aoff0];
      b[ni][1] = *(const short8*)&Bbase[so + ni * 1024 + aoff1];
    }
    if (s < 15) {
      SA(gA1, 1, s + 1, nbuf); SA(gA3, 3, s + 1, nbuf);
      SB(gB0, 0, s + 1, nbuf); SB(gB1, 1, s + 1, nbuf);
      SB(gB2, 2, s + 1, nbuf); SB(gB3, 3, s + 1, nbuf);
    }
    __builtin_amdgcn_s_barrier();
    asm volatile("s_waitcnt lgkmcnt(0)" ::: "memory");
    __builtin_amdgcn_sched_barrier(0);
    __builtin_amdgcn_s_setprio(1);
#pragma unroll
    for (int mi = 0; mi < 4; mi++)
#pragma unroll
      for (int ni = 0; ni < 2; ni++) {
        acc[mi][ni] = MFMA(a[mi][0], b[ni][0], acc[mi][ni]);
        acc[mi][ni] = MFMA(a[mi][1], b[ni][1], acc[mi][ni]);
      }
    __builtin_amdgcn_s_setprio(0);
    __builtin_amdgcn_s_barrier();
    // -------- p1: read B(nh1); compute mh0 x nh1 ---------------------------
#pragma unroll
    for (int ni = 2; ni < 4; ni++) {
      b[ni][0] = *(const short8*)&Bbase[so + ni * 1024 + aoff0];
      b[ni][1] = *(const short8*)&Bbase[so + ni * 1024 + aoff1];
    }
    __builtin_amdgcn_s_barrier();
    asm volatile("s_waitcnt lgkmcnt(0)" ::: "memory");
    __builtin_amdgcn_sched_barrier(0);
    __builtin_amdgcn_s_setprio(1);
#pragma unroll
    for (int mi = 0; mi < 4; mi++)
#pragma unroll
      for (int ni = 2; ni < 4; ni++) {
        acc[mi][ni] = MFMA(a[mi][0], b[ni][0], acc[mi][ni]);
        acc[mi][ni] = MFMA(a[mi][1], b[ni][1], acc[mi][ni]);
      }
    __builtin_amdgcn_s_setprio(0);
    __builtin_amdgcn_s_barrier();
    // -------- p2: read A(mh1); stage A(s+2)q0,q2 (same buf, consumed rows) -
#pragma unroll
    for (int mi = 0; mi < 4; mi++) {
      a[mi][0] = *(const short8*)&Abase[so + (mi + 4) * 1024 + aoff0];
      a[mi][1] = *(const short8*)&Abase[so + (mi + 4) * 1024 + aoff1];
    }
    if (s < 14) { SA(gA0, 0, s + 2, buf); SA(gA2, 2, s + 2, buf); }
    __builtin_amdgcn_s_barrier();
    asm volatile("s_waitcnt lgkmcnt(0)" ::: "memory");
    __builtin_amdgcn_sched_barrier(0);
    __builtin_amdgcn_s_setprio(1);
#pragma unroll
    for (int mi = 0; mi < 4; mi++)
#pragma unroll
      for (int ni = 0; ni < 2; ni++) {
        acc[mi + 4][ni] = MFMA(a[mi][0], b[ni][0], acc[mi + 4][ni]);
        acc[mi + 4][ni] = MFMA(a[mi][1], b[ni][1], acc[mi + 4][ni]);
      }
    __builtin_amdgcn_s_setprio(0);
    __builtin_amdgcn_s_barrier();
    // -------- p3: compute mh1 x nh1; counted-vmcnt checkpoint --------------
    __builtin_amdgcn_s_setprio(1);
#pragma unroll
    for (int mi = 0; mi < 4; mi++)
#pragma unroll
      for (int ni = 2; ni < 4; ni++) {
        acc[mi + 4][ni] = MFMA(a[mi][0], b[ni][0], acc[mi + 4][ni]);
        acc[mi + 4][ni] = MFMA(a[mi][1], b[ni][1], acc[mi + 4][ni]);
      }
    __builtin_amdgcn_s_setprio(0);
    if (s < 14) { asm volatile("s_waitcnt vmcnt(2)" ::: "memory"); }
    else        { asm volatile("s_waitcnt vmcnt(0)" ::: "memory"); }
    __builtin_amdgcn_s_barrier();
  }

  // ---------------- epilogue: per-wave LDS transpose -> short8 stores ------
  __syncthreads();
  unsigned short* scr = &LDSf[wid * 8192];
  const int cat = c0 >> 10;                        // 0=K 1=Q 2=V (block-uniform)
  const int h   = ((c0 + wc * 64) >> 6) & 15;      // wave-uniform
  const int bb  = (m0 + wr * 128) >> 11;
  const int n0b = (m0 + wr * 128) & (N_ - 1);
  const int l8 = lane & 7, lh = lane >> 3;
  if (cat < 2) {
    const float scale = (cat == 1) ? 0.18033688011112042f : 1.0f;  // Q: 0.125*log2e
    float bias[4];
#pragma unroll
    for (int ni = 0; ni < 4; ni++) bias[ni] = bkqv[h * E3_ + cat * 64 + ni * 16 + l16];
#pragma unroll
    for (int mi = 0; mi < 8; mi++)
#pragma unroll
      for (int ni = 0; ni < 4; ni++)
#pragma unroll
        for (int r = 0; r < 4; r++) {
          int rl = mi * 16 + quad * 4 + r, cl = ni * 16 + l16;
          scr[rl * 64 + ((((cl >> 3) ^ rl) & 7) * 8) + (cl & 7)] =
              f2bf((acc[mi][ni][r] + bias[ni]) * scale);
        }
    asm volatile("s_waitcnt lgkmcnt(0)" ::: "memory");  // wave-private scratch
    unsigned short* dst = (cat == 0) ? Kb : Qb;
#pragma unroll
    for (int j = 0; j < 16; j++) {
      int rl = j * 8 + lh;                              // rl&7 == lh
      short8 vv = *(const short8*)&scr[rl * 64 + ((l8 ^ lh) * 8)];
      *(short8*)&dst[((size_t)(bb * H_ + h) * N_ + n0b + rl) * DH_ + l8 * 8] = vv;
    }
  } else {
    float bias[4];
#pragma unroll
    for (int ni = 0; ni < 4; ni++) bias[ni] = bkqv[h * E3_ + 128 + ni * 16 + l16];
#pragma unroll
    for (int mi = 0; mi < 8; mi++)
#pragma unroll
      for (int ni = 0; ni < 4; ni++)
#pragma unroll
        for (int r = 0; r < 4; r++) {
          int nl = mi * 16 + quad * 4 + r, e = ni * 16 + l16;
          scr[e * 128 + ((((nl >> 3) ^ e) & 15) * 8) + (nl & 7)] =
              f2bf(acc[mi][ni][r] + bias[ni]);
        }
    asm volatile("s_waitcnt lgkmcnt(0)" ::: "memory");
#pragma unroll
    for (int j = 0; j < 16; j++) {
      int e = (j & 7) * 8 + lh;
      int nc = l8 + (j >> 3) * 8;
      short8 vv = *(const short8*)&scr[e * 128 + (((nc ^ e) & 15) * 8)];
      *(short8*)&Vt[((size_t)(bb * H_ + h) * DH_ + e) * N_ + n0b + nc * 8] = vv;
    }
  }
#undef SA
#undef SB
}

// ---------------- flash attention: 128-row blocks, 32 q-rows/wave -----------
// LDS-port fix: each wave owns TWO 16-row q-groups, so every kf/vf fragment
// feeds 2x the MFMA (reads/MFMA 1.13 -> 0.63). Swapped QK^T + packed f2bf
// P-write + counted-vmcnt 2-deep pipeline all carried from R8 (proven).
// Masking: last two tiles, key_rel = di*64+... vs row_rel.
__global__ __launch_bounds__(256) void k_flash(const unsigned short* __restrict__ Qb,
                                               const unsigned short* __restrict__ Kb,
                                               const unsigned short* __restrict__ Vt,
                                               unsigned short* __restrict__ sab) {
  int bh = blockIdx.x;
  int y = blockIdx.y, g8 = y >> 3, o = y & 7;
  int qb = (g8 == 0) ? o : 15 - o;      // light half then heavy half -> CU pair sums ~const
  int q0b = qb * 128;
  int wave = threadIdx.x >> 6;
  int lane = threadIdx.x & 63, quad = lane >> 4, l16 = lane & 15;
  const unsigned short* Qp = Qb + (size_t)bh * N_ * DH_;
  const unsigned short* Kp = Kb + (size_t)bh * N_ * DH_;
  const unsigned short* Vp = Vt + (size_t)bh * DH_ * N_;
  __shared__ unsigned short Klds[2][2 * 64 * 32];   // [buf][half][row][32]
  __shared__ unsigned short Vlds[2][2 * 64 * 32];
  __shared__ unsigned short Plds[4][2 * 16 * 64];   // per-wave, 2 groups, swizzled
  unsigned short* P = Plds[wave];

  int q0w = q0b + wave * 32;
  short8 qf[2][2];
#pragma unroll
  for (int g = 0; g < 2; g++) {
    qf[g][0] = *(const short8*)&Qp[(q0w + g * 16 + l16) * DH_ + quad * 8];
    qf[g][1] = *(const short8*)&Qp[(q0w + g * 16 + l16) * DH_ + 32 + quad * 8];
  }

  int swz = ((lane & 3) ^ ((lane >> 3) & 3)) * 8;
  const unsigned short* gK = Kp + (size_t)(wave * 16 + (lane >> 2)) * DH_ + swz;
  const unsigned short* gV = Vp + (size_t)(wave * 16 + (lane >> 2)) * N_ + swz;
  int lofs = (wave * 16) * 32;
  int xr = ((l16 >> 1) & 3) * 8;
  int pxr = l16 & 7;

#define FSTAGE(ii, bb) do {                                              \
    size_t ko_ = (size_t)(ii) * 64 * DH_; int vo_ = (ii) * 64;           \
    GL_LDS16(gK + ko_,      &Klds[bb][lofs]);                            \
    GL_LDS16(gK + ko_ + 32, &Klds[bb][lofs + 64 * 32]);                  \
    GL_LDS16(gV + vo_,      &Vlds[bb][lofs]);                            \
    GL_LDS16(gV + vo_ + 32, &Vlds[bb][lofs + 64 * 32]);                  \
  } while (0)

  floatx4 O[2][4];
  float lr[2] = {0.f, 0.f};
#pragma unroll
  for (int g = 0; g < 2; g++)
#pragma unroll
    for (int dt = 0; dt < 4; dt++) O[g][dt] = (floatx4){0.f, 0.f, 0.f, 0.f};

  int nt = (q0b >> 6) + 2;               // >= 2 always
  FSTAGE(0, 0);
  FSTAGE(1, 1);

  for (int i = 0; i < nt; i++) {
    int buf = i & 1;
    if (i + 1 < nt) { asm volatile("s_waitcnt vmcnt(4)" ::: "memory"); }
    else            { asm volatile("s_waitcnt vmcnt(0)" ::: "memory"); }
    __builtin_amdgcn_s_barrier();          // collective: tile i fully in LDS
    __builtin_amdgcn_sched_barrier(0);
    short8 kf[4][2], vf[4][2];
#pragma unroll
    for (int c = 0; c < 4; c++) {
      kf[c][0] = *(const short8*)&Klds[buf][(c * 16 + l16) * 32 + ((quad * 8) ^ xr)];
      kf[c][1] = *(const short8*)&Klds[buf][(64 + c * 16 + l16) * 32 + ((quad * 8) ^ xr)];
      vf[c][0] = *(const short8*)&Vlds[buf][(c * 16 + l16) * 32 + ((quad * 8) ^ xr)];
      vf[c][1] = *(const short8*)&Vlds[buf][(64 + c * 16 + l16) * 32 + ((quad * 8) ^ xr)];
    }
#pragma unroll
    for (int g = 0; g < 2; g++) {
      floatx4 s[4];
      __builtin_amdgcn_s_setprio(1);
#pragma unroll
      for (int c = 0; c < 4; c++) {        // SWAPPED: S^T[key][q]
        s[c] = (floatx4){0.f, 0.f, 0.f, 0.f};
        s[c] = MFMA(kf[c][0], qf[g][0], s[c]);
        s[c] = MFMA(kf[c][1], qf[g][1], s[c]);
      }
      __builtin_amdgcn_s_setprio(0);
      if (i >= nt - 2) {                   // diagonal region: mask key > q-row
        int di = i - (nt - 2);
        int rowrel = wave * 32 + g * 16 + l16;
#pragma unroll
        for (int c = 0; c < 4; c++)
#pragma unroll
          for (int r = 0; r < 4; r++) {
            int keyrel = di * 64 + c * 16 + quad * 4 + r;
            if (keyrel > rowrel) s[c][r] = -1e30f;
          }
      }
#pragma unroll
      for (int c = 0; c < 4; c++)
#pragma unroll
        for (int r = 0; r < 4; r++)
          s[c][r] = __builtin_amdgcn_exp2f(s[c][r]);   // log2-scaled scores
#pragma unroll
      for (int c = 0; c < 4; c++)
        lr[g] += (s[c][0] + s[c][1]) + (s[c][2] + s[c][3]);
      // pack (f2bf) & write P_g[q=l16][key=c*16+quad*4..+3]
#pragma unroll
      for (int c = 0; c < 4; c++) {
        unsigned plo = (unsigned)f2bf(s[c][0]) | ((unsigned)f2bf(s[c][1]) << 16);
        unsigned phi = (unsigned)f2bf(s[c][2]) | ((unsigned)f2bf(s[c][3]) << 16);
        int ch = c * 2 + (quad >> 1);      // key>>3
        uint2 pk; pk.x = plo; pk.y = phi;
        *(uint2*)&P[g * 1024 + l16 * 64 + ((ch ^ pxr) * 8) + (quad & 1) * 4] = pk;
      }
    }
    __asm__ volatile("s_waitcnt lgkmcnt(0)" ::: "memory");
    short8 pa[2][2];
#pragma unroll
    for (int g = 0; g < 2; g++) {
      pa[g][0] = *(const short8*)&P[g * 1024 + l16 * 64 + ((quad ^ pxr) * 8)];
      pa[g][1] = *(const short8*)&P[g * 1024 + l16 * 64 + (((quad + 4) ^ pxr) * 8)];
    }
    __asm__ volatile("" ::: "memory");
    __builtin_amdgcn_s_setprio(1);
#pragma unroll
    for (int g = 0; g < 2; g++)
#pragma unroll
      for (int dt = 0; dt < 4; dt++) {
        O[g][dt] = MFMA(pa[g][0], vf[dt][0], O[g][dt]);
        O[g][dt] = MFMA(pa[g][1], vf[dt][1], O[g][dt]);
      }
    __builtin_amdgcn_s_setprio(0);
    __builtin_amdgcn_s_barrier();          // all waves done reading buf(i&1)
    __builtin_amdgcn_sched_barrier(0);
    if (i + 2 < nt) FSTAGE(i + 2, buf);    // overwrite just-consumed buffer
  }
#undef FSTAGE

  // row-sum per group: lane holds partial for q-row l16; reduce across quad
#pragma unroll
  for (int g = 0; g < 2; g++) {
    lr[g] += __shfl_xor(lr[g], 16);
    lr[g] += __shfl_xor(lr[g], 32);
  }

  int b = bh >> 4, h = bh & 15;
#pragma unroll
  for (int g = 0; g < 2; g++)
#pragma unroll
    for (int r = 0; r < 4; r++) {
      float inv = 1.0f / __shfl(lr[g], quad * 4 + r);   // sum for q-row quad*4+r
      size_t base = ((size_t)b * N_ + q0w + g * 16 + quad * 4 + r) * D_ + h * DH_;
#pragma unroll
      for (int dt = 0; dt < 4; dt++) sab[base + dt * 16 + l16] = f2bf(O[g][dt][r] * inv);
    }
}

// ------- output projection: 128x128 tile, BK=64, 8-wave, counted vmcnt ------
// (R8-proven revert) 2-deep prefetch, vmcnt(4) per K-step, chunk^(row&7)
// swizzle both-sides, setprio around MFMA cluster, XCD-mapped c0.
__global__ __launch_bounds__(512) void k_proj(const unsigned short* __restrict__ sab,
                                              const unsigned short* __restrict__ Wpb,
                                              const float* __restrict__ bproj,
                                              float* __restrict__ out) {
  __shared__ unsigned short LDSp[32768];   // 64 KiB: A[2][128][64] | B[2][128][64]
  const int t = threadIdx.x;
  const int wid = t >> 6, lane = t & 63, quad = lane >> 4, l16 = lane & 15;
  const int wr = wid >> 1, wc = wid & 1;          // 4 x 2 waves
  const int bid = blockIdx.x;
  const int m0 = (bid >> 3) * 128, c0 = (bid & 7) * 128;

  floatx4 acc[2][4];
#pragma unroll
  for (int i = 0; i < 2; i++)
#pragma unroll
    for (int j = 0; j < 4; j++) acc[i][j] = (floatx4){0.f, 0.f, 0.f, 0.f};

  const int slr = t >> 3;                          // 0..63
  const int sco = ((t & 7) ^ (slr & 7)) * 8;       // inverse-swizzled source
  const unsigned short* gA0 = sab + (size_t)(m0 +  0 + slr) * D_ + sco;
  const unsigned short* gA1 = sab + (size_t)(m0 + 64 + slr) * D_ + sco;
  const unsigned short* gB0 = Wpb + (size_t)(c0 +  0 + slr) * D_ + sco;
  const unsigned short* gB1 = Wpb + (size_t)(c0 + 64 + slr) * D_ + sco;
#define PA(gp, q, s, bb) GL_LDS16((gp) + (s) * 64, &LDSp[(bb) * 8192 + (q) * 4096 + t * 8])
#define PB(gp, q, s, bb) GL_LDS16((gp) + (s) * 64, &LDSp[16384 + (bb) * 8192 + (q) * 4096 + t * 8])

  const int aoff0 = ((quad)     ^ (l16 & 7)) * 8;  // k-chunk 0..3
  const int aoff1 = ((4 + quad) ^ (l16 & 7)) * 8;  // k-chunk 4..7
  const unsigned short* Abase = &LDSp[(wr * 32 + l16) * 64];
  const unsigned short* Bbase = &LDSp[16384 + (wc * 64 + l16) * 64];

  // prologue: tiles 0 and 1 (4 issues each)
  PA(gA0, 0, 0, 0); PA(gA1, 1, 0, 0); PB(gB0, 0, 0, 0); PB(gB1, 1, 0, 0);
  PA(gA0, 0, 1, 1); PA(gA1, 1, 1, 1); PB(gB0, 0, 1, 1); PB(gB1, 1, 1, 1);

  for (int i = 0; i < 16; i++) {
    const int buf = i & 1;
    const int so = buf * 8192;
    if (i + 1 < 16) { asm volatile("s_waitcnt vmcnt(4)" ::: "memory"); }
    else            { asm volatile("s_waitcnt vmcnt(0)" ::: "memory"); }
    __builtin_amdgcn_s_barrier();
    __builtin_amdgcn_sched_barrier(0);
    short8 a[2][2], b[4][2];
#pragma unroll
    for (int mi = 0; mi < 2; mi++) {
      a[mi][0] = *(const short8*)&Abase[so + mi * 1024 + aoff0];
      a[mi][1] = *(const short8*)&Abase[so + mi * 1024 + aoff1];
    }
#pragma unroll
    for (int ni = 0; ni < 4; ni++) {
      b[ni][0] = *(const short8*)&Bbase[so + ni * 1024 + aoff0];
      b[ni][1] = *(const short8*)&Bbase[so + ni * 1024 + aoff1];
    }
    __builtin_amdgcn_s_setprio(1);
#pragma unroll
    for (int mi = 0; mi < 2; mi++)
#pragma unroll
      for (int ni = 0; ni < 4; ni++) {
        acc[mi][ni] = MFMA(a[mi][0], b[ni][0], acc[mi][ni]);
        acc[mi][ni] = MFMA(a[mi][1], b[ni][1], acc[mi][ni]);
      }
    __builtin_amdgcn_s_setprio(0);
    __builtin_amdgcn_s_barrier();
    __builtin_amdgcn_sched_barrier(0);
    if (i + 2 < 16) {
      PA(gA0, 0, i + 2, buf); PA(gA1, 1, i + 2, buf);
      PB(gB0, 0, i + 2, buf); PB(gB1, 1, i + 2, buf);
    }
  }

#pragma unroll
  for (int mi = 0; mi < 2; mi++)
#pragma unroll
    for (int ni = 0; ni < 4; ni++) {
      int col = c0 + wc * 64 + ni * 16 + l16;
      int grow = m0 + wr * 32 + mi * 16 + quad * 4;
      float bias = bproj[col];
#pragma unroll
      for (int r = 0; r < 4; r++)
        out[(size_t)(grow + r) * D_ + col] = acc[mi][ni][r] + bias;
    }
#undef PA
#undef PB
}

extern "C" void kernel_launch(void* const* d_in, const int* in_sizes, int n_in,
                              void* d_out, int out_size, void* d_ws, size_t ws_size,
                              hipStream_t stream) {
  const float* x     = (const float*)d_in[0];
  const float* Wkqv  = (const float*)d_in[1];
  const float* bkqv  = (const float*)d_in[2];
  const float* Wproj = (const float*)d_in[3];
  const float* bproj = (const float*)d_in[4];
  float* out = (float*)d_out;

  char* w = (char*)d_ws;
  unsigned short* Xb  = (unsigned short*)(w);                       // 8 MiB  [B*N][D]
  unsigned short* Wt  = (unsigned short*)(w + (8u  << 20));         // 6 MiB  [3072][1024] (cat-permuted)
  unsigned short* Wpb = (unsigned short*)(w + (14u << 20));         // 2 MiB  [D][D]
  unsigned short* Qb  = (unsigned short*)(w + (16u << 20));         // 8 MiB  [B*H][N][DH] (pre-scaled by 0.125*log2e)
  unsigned short* Kb  = (unsigned short*)(w + (24u << 20));         // 8 MiB  [B*H][N][DH]
  unsigned short* Vt  = (unsigned short*)(w + (32u << 20));         // 8 MiB  [B*H][DH][N]
  unsigned short* sa  = (unsigned short*)(w + (40u << 20));         // 8 MiB  [B*N][D]

  k_prep<<<2048 + 768 + 512, 256, 0, stream>>>(x, Wkqv, Wproj, Xb, Wt, Wpb);
  k_qkv<<<dim3(B_ * N_ / 256, 3072 / 256), 512, 0, stream>>>(Xb, Wt, bkqv, Qb, Kb, Vt);
  k_flash<<<dim3(B_ * H_, N_ / 128), 256, 0, stream>>>(Qb, Kb, Vt, sa);
  k_proj<<<(B_ * N_ / 128) * (D_ / 128), 512, 0, stream>>>(sa, Wpb, bproj, out);
}

// Round 11
// 168.426 us; speedup vs baseline: 1.0547x; 1.0547x over previous
//
#include <hip/hip_runtime.h>
#include <hip/hip_bf16.h>
#include <cstdint>
#include <cstddef>

#define B_  2
#define N_  2048
#define D_  1024
#define H_  16
#define DH_ 64
#define E3_ 192   // 3*DH

typedef __attribute__((ext_vector_type(8))) short short8;
typedef __attribute__((ext_vector_type(8))) unsigned short ushort8v;
typedef __attribute__((ext_vector_type(4))) float floatx4;

static __device__ __forceinline__ unsigned short f2bf(float f) {
  union { float f; unsigned u; } c; c.f = f;
  unsigned r = c.u + 0x7fffu + ((c.u >> 16) & 1u);   // RNE
  return (unsigned short)(r >> 16);
}

#define MFMA(a,b,c) __builtin_amdgcn_mfma_f32_16x16x32_bf16((a),(b),(c),0,0,0)

// async global->LDS, 16B per lane, dest = uniform base + lane*16
#define GL_LDS16(g, l) __builtin_amdgcn_global_load_lds( \
    (const __attribute__((address_space(1))) void*)(g),  \
    (__attribute__((address_space(3))) void*)(l), 16, 0, 0)

// ---------------- merged prep: x->bf16 | W_kqv transpose | Wproj->bf16 ------
// grid = 2048 (x) + 768 (twkqv) + 512 (Wproj)
__global__ __launch_bounds__(256) void k_prep(const float* __restrict__ x,
                                              const float* __restrict__ Wkqv,
                                              const float* __restrict__ Wproj,
                                              unsigned short* __restrict__ Xb,
                                              unsigned short* __restrict__ Wt,
                                              unsigned short* __restrict__ Wpb) {
  __shared__ float tile[64][65];
  int bx = blockIdx.x, t = threadIdx.x;
  if (bx < 2048 || bx >= 2816) {            // plain f2bf converts
    const float* in = (bx < 2048) ? x : Wproj;
    unsigned short* out = (bx < 2048) ? Xb : Wpb;
    int i = ((bx < 2048) ? bx : bx - 2816) * 256 + t;
    const float4* p = (const float4*)in + (size_t)i * 2;
    float4 a = p[0], b = p[1];
    ushort8v o;
    o[0]=f2bf(a.x); o[1]=f2bf(a.y); o[2]=f2bf(a.z); o[3]=f2bf(a.w);
    o[4]=f2bf(b.x); o[5]=f2bf(b.y); o[6]=f2bf(b.z); o[7]=f2bf(b.w);
    *((ushort8v*)out + i) = o;
    return;
  }
  // W_kqv [h][d][e] -> Wt [cat][h][e'][d]  (col' = cat*1024 + h*64 + e')
  int idx = bx - 2048;
  int d0 = (idx & 15) * 64, rem = idx >> 4;
  int cat = rem % 3, h = rem / 3, e0 = cat * 64;
  const float* Wp = Wkqv + (size_t)h * D_ * E3_;
  int dr = t >> 2, ec = (t & 3) * 16;
#pragma unroll
  for (int j = 0; j < 16; j += 4) {
    float4 wv = *(const float4*)&Wp[(size_t)(d0 + dr) * E3_ + e0 + ec + j];
    tile[dr][ec + j + 0] = wv.x; tile[dr][ec + j + 1] = wv.y;
    tile[dr][ec + j + 2] = wv.z; tile[dr][ec + j + 3] = wv.w;
  }
  __syncthreads();
  int er = t >> 2, dc = (t & 3) * 16;
  ushort8v o0, o1;
#pragma unroll
  for (int j = 0; j < 8; j++) o0[j] = f2bf(tile[dc + j][er]);
#pragma unroll
  for (int j = 0; j < 8; j++) o1[j] = f2bf(tile[dc + 8 + j][er]);
  size_t o = ((size_t)(cat * 1024 + h * 64 + er)) * D_ + d0 + dc;
  *(ushort8v*)&Wt[o]     = o0;
  *(ushort8v*)&Wt[o + 8] = o1;
}

// ------------- QKV GEMM: 128x128 tile, BK=64, 4-wave, counted vmcnt ---------
// Occupancy fix: 256^2 grid was 192 blocks (25% CUs idle, 1 block/CU, 6 total
// waves/CU). 128^2 -> 768 blocks = 3/CU, 2 co-resident (64 KiB LDS), 12 total
// waves/CU (m114 co-residency overlap). Pipeline = R8-proj's proven loop
// (2-deep prefetch, vmcnt(8)/step, chunk^(row&7) swizzle both-sides).
// Epilogue = R1's verified 128^2 per-wave 64x64 scratch transpose.
// Q pre-scaled by 0.125*log2e (softmax in log2 domain downstream).
__global__ __launch_bounds__(256, 2) void k_qkv(const unsigned short* __restrict__ Xb,
                                                const unsigned short* __restrict__ Wt,
                                                const float* __restrict__ bkqv,
                                                unsigned short* __restrict__ Qb,
                                                unsigned short* __restrict__ Kb,
                                                unsigned short* __restrict__ Vt) {
  __shared__ unsigned short LDSq[32768];   // 64 KiB: A[2][128][64] | B[2][128][64]
  const int t = threadIdx.x;
  const int wid = t >> 6, lane = t & 63, quad = lane >> 4, l16 = lane & 15;
  const int wm = (wid >> 1) * 64, wn = (wid & 1) * 64;
  const int m0 = blockIdx.x * 128, c0 = blockIdx.y * 128;

  floatx4 acc[4][4];
#pragma unroll
  for (int i = 0; i < 4; i++)
#pragma unroll
    for (int j = 0; j < 4; j++) acc[i][j] = (floatx4){0.f, 0.f, 0.f, 0.f};

  // staging: thread t covers quarter-local row t>>3, swizzled chunk (t&7)^(row&7)
  const int slr = t >> 3;
  const int sco = ((t & 7) ^ (slr & 7)) * 8;
  const unsigned short* gA0 = Xb + (size_t)(m0 +  0 + slr) * D_ + sco;
  const unsigned short* gA1 = Xb + (size_t)(m0 + 32 + slr) * D_ + sco;
  const unsigned short* gA2 = Xb + (size_t)(m0 + 64 + slr) * D_ + sco;
  const unsigned short* gA3 = Xb + (size_t)(m0 + 96 + slr) * D_ + sco;
  const unsigned short* gB0 = Wt + (size_t)(c0 +  0 + slr) * D_ + sco;
  const unsigned short* gB1 = Wt + (size_t)(c0 + 32 + slr) * D_ + sco;
  const unsigned short* gB2 = Wt + (size_t)(c0 + 64 + slr) * D_ + sco;
  const unsigned short* gB3 = Wt + (size_t)(c0 + 96 + slr) * D_ + sco;
#define SA(qq, s, bb) GL_LDS16(gA##qq + (s) * 64, &LDSq[(bb) * 8192 + (qq) * 2048 + t * 8])
#define SB(qq, s, bb) GL_LDS16(gB##qq + (s) * 64, &LDSq[16384 + (bb) * 8192 + (qq) * 2048 + t * 8])
#define STAGE(s, bb) do { SA(0,s,bb); SA(1,s,bb); SA(2,s,bb); SA(3,s,bb); \
                          SB(0,s,bb); SB(1,s,bb); SB(2,s,bb); SB(3,s,bb); } while (0)

  const int aoff0 = ((quad)     ^ (l16 & 7)) * 8;  // k-chunk 0..3
  const int aoff1 = ((4 + quad) ^ (l16 & 7)) * 8;  // k-chunk 4..7

  // prologue: tiles 0 and 1 (8 issues each; 16 outstanding)
  STAGE(0, 0);
  STAGE(1, 1);

  for (int i = 0; i < 16; i++) {
    const int buf = i & 1;
    const int soA = buf * 8192, soB = 16384 + buf * 8192;
    if (i + 1 < 16) { asm volatile("s_waitcnt vmcnt(8)" ::: "memory"); }
    else            { asm volatile("s_waitcnt vmcnt(0)" ::: "memory"); }
    __builtin_amdgcn_s_barrier();
    __builtin_amdgcn_sched_barrier(0);
    short8 a[4][2], b[4][2];
#pragma unroll
    for (int mi = 0; mi < 4; mi++) {
      a[mi][0] = *(const short8*)&LDSq[soA + (wm + mi * 16 + l16) * 64 + aoff0];
      a[mi][1] = *(const short8*)&LDSq[soA + (wm + mi * 16 + l16) * 64 + aoff1];
    }
#pragma unroll
    for (int ni = 0; ni < 4; ni++) {
      b[ni][0] = *(const short8*)&LDSq[soB + (wn + ni * 16 + l16) * 64 + aoff0];
      b[ni][1] = *(const short8*)&LDSq[soB + (wn + ni * 16 + l16) * 64 + aoff1];
    }
    __builtin_amdgcn_s_setprio(1);
#pragma unroll
    for (int mi = 0; mi < 4; mi++)
#pragma unroll
      for (int ni = 0; ni < 4; ni++) {
        acc[mi][ni] = MFMA(a[mi][0], b[ni][0], acc[mi][ni]);
        acc[mi][ni] = MFMA(a[mi][1], b[ni][1], acc[mi][ni]);
      }
    __builtin_amdgcn_s_setprio(0);
    __builtin_amdgcn_s_barrier();
    __builtin_amdgcn_sched_barrier(0);
    if (i + 2 < 16) STAGE(i + 2, buf);
  }
#undef SA
#undef SB
#undef STAGE

  // ---------------- epilogue: per-wave 64x64 scratch -> short8 stores ------
  __syncthreads();
  unsigned short* scr = &LDSq[wid * 4096];         // 8 KiB/wave
  const int cat = c0 >> 10;                        // 0=K 1=Q 2=V (block-uniform)
  const int h   = ((c0 + wn) >> 6) & 15;           // wave-uniform
  const int bb  = (m0 + wm) >> 11;
  const int n0b = (m0 + wm) & (N_ - 1);
  const int l8 = lane & 7, lh = lane >> 3;
  if (cat < 2) {
    const float scale = (cat == 1) ? 0.18033688011112042f : 1.0f;  // Q: 0.125*log2e
    float bias[4];
#pragma unroll
    for (int ni = 0; ni < 4; ni++) bias[ni] = bkqv[h * E3_ + cat * 64 + ni * 16 + l16];
#pragma unroll
    for (int mi = 0; mi < 4; mi++)
#pragma unroll
      for (int ni = 0; ni < 4; ni++)
#pragma unroll
        for (int r = 0; r < 4; r++) {
          int rl = mi * 16 + quad * 4 + r, cl = ni * 16 + l16;
          scr[rl * 64 + (((cl >> 3) ^ (rl & 7)) * 8) + (cl & 7)] =
              f2bf((acc[mi][ni][r] + bias[ni]) * scale);
        }
    asm volatile("s_waitcnt lgkmcnt(0)" ::: "memory");  // wave-private scratch
    unsigned short* dst = (cat == 0) ? Kb : Qb;
#pragma unroll
    for (int j = 0; j < 8; j++) {
      int rl = j * 8 + lh;                              // rl&7 == lh
      short8 vv = *(const short8*)&scr[rl * 64 + ((l8 ^ lh) * 8)];
      *(short8*)&dst[((size_t)(bb * H_ + h) * N_ + n0b + rl) * DH_ + l8 * 8] = vv;
    }
  } else {
    float bias[4];
#pragma unroll
    for (int ni = 0; ni < 4; ni++) bias[ni] = bkqv[h * E3_ + 128 + ni * 16 + l16];
#pragma unroll
    for (int mi = 0; mi < 4; mi++)
#pragma unroll
      for (int ni = 0; ni < 4; ni++)
#pragma unroll
        for (int r = 0; r < 4; r++) {
          int nl = mi * 16 + quad * 4 + r, e = ni * 16 + l16;
          scr[e * 64 + (((nl >> 3) ^ (e & 7)) * 8) + (nl & 7)] =
              f2bf(acc[mi][ni][r] + bias[ni]);
        }
    asm volatile("s_waitcnt lgkmcnt(0)" ::: "memory");
#pragma unroll
    for (int j = 0; j < 8; j++) {
      int le = j * 8 + lh;                              // le&7 == lh
      short8 vv = *(const short8*)&scr[le * 64 + ((l8 ^ lh) * 8)];
      *(short8*)&Vt[((size_t)(bb * H_ + h) * DH_ + le) * N_ + n0b + l8 * 8] = vv;
    }
  }
}

// ---------------- flash attention: swapped QK^T + packed P-write ------------
// (R8-proven) S^T = MFMA(K, Q); packed f2bf P-write as b64; counted-vmcnt
// 2-deep pipeline; scalar row-sum + 2 shfl.
__global__ __launch_bounds__(256) void k_flash(const unsigned short* __restrict__ Qb,
                                               const unsigned short* __restrict__ Kb,
                                               const unsigned short* __restrict__ Vt,
                                               unsigned short* __restrict__ sab) {
  int bh = blockIdx.x;
  int yr = blockIdx.y, g = yr >> 3, o = yr & 7;
  int qb = (g == 0) ? o : (g == 1) ? 31 - o : (g == 2) ? 8 + o : 23 - o;
  int q0b = qb * 64;
  int wave = threadIdx.x >> 6;
  int lane = threadIdx.x & 63, quad = lane >> 4, l16 = lane & 15;
  const unsigned short* Qp = Qb + (size_t)bh * N_ * DH_;
  const unsigned short* Kp = Kb + (size_t)bh * N_ * DH_;
  const unsigned short* Vp = Vt + (size_t)bh * DH_ * N_;
  __shared__ unsigned short Klds[2][2 * 64 * 32];   // [buf][half][row][32]
  __shared__ unsigned short Vlds[2][2 * 64 * 32];
  __shared__ unsigned short Plds[4][16 * 64];       // per-wave private, swizzled
  unsigned short* P = Plds[wave];

  int q0w = q0b + wave * 16;
  short8 qf0 = *(const short8*)&Qp[(q0w + l16) * DH_ + quad * 8];
  short8 qf1 = *(const short8*)&Qp[(q0w + l16) * DH_ + 32 + quad * 8];

  int swz = ((lane & 3) ^ ((lane >> 3) & 3)) * 8;
  const unsigned short* gK = Kp + (size_t)(wave * 16 + (lane >> 2)) * DH_ + swz;
  const unsigned short* gV = Vp + (size_t)(wave * 16 + (lane >> 2)) * N_ + swz;
  int lofs = (wave * 16) * 32;
  int xr = ((l16 >> 1) & 3) * 8;
  int pxr = l16 & 7;

#define FSTAGE(ii, bb) do {                                              \
    size_t ko_ = (size_t)(ii) * 64 * DH_; int vo_ = (ii) * 64;           \
    GL_LDS16(gK + ko_,      &Klds[bb][lofs]);                            \
    GL_LDS16(gK + ko_ + 32, &Klds[bb][lofs + 64 * 32]);                  \
    GL_LDS16(gV + vo_,      &Vlds[bb][lofs]);                            \
    GL_LDS16(gV + vo_ + 32, &Vlds[bb][lofs + 64 * 32]);                  \
  } while (0)

  floatx4 O[4];
  float lr = 0.f;
#pragma unroll
  for (int r = 0; r < 4; r++) O[r] = (floatx4){0.f, 0.f, 0.f, 0.f};

  int nt = (q0b >> 6) + 1;
  FSTAGE(0, 0);
  if (nt > 1) FSTAGE(1, 1);

  for (int i = 0; i < nt; i++) {
    int buf = i & 1;
    if (i + 1 < nt) { asm volatile("s_waitcnt vmcnt(4)" ::: "memory"); }
    else            { asm volatile("s_waitcnt vmcnt(0)" ::: "memory"); }
    __builtin_amdgcn_s_barrier();          // collective: tile i fully in LDS
    __builtin_amdgcn_sched_barrier(0);
    short8 kf[4][2], vf[4][2];
#pragma unroll
    for (int c = 0; c < 4; c++) {
      kf[c][0] = *(const short8*)&Klds[buf][(c * 16 + l16) * 32 + ((quad * 8) ^ xr)];
      kf[c][1] = *(const short8*)&Klds[buf][(64 + c * 16 + l16) * 32 + ((quad * 8) ^ xr)];
      vf[c][0] = *(const short8*)&Vlds[buf][(c * 16 + l16) * 32 + ((quad * 8) ^ xr)];
      vf[c][1] = *(const short8*)&Vlds[buf][(64 + c * 16 + l16) * 32 + ((quad * 8) ^ xr)];
    }
    floatx4 s[4];
    __builtin_amdgcn_s_setprio(1);
#pragma unroll
    for (int c = 0; c < 4; c++) {          // SWAPPED: S^T[key][q]
      s[c] = (floatx4){0.f, 0.f, 0.f, 0.f};
      s[c] = MFMA(kf[c][0], qf0, s[c]);
      s[c] = MFMA(kf[c][1], qf1, s[c]);
    }
    __builtin_amdgcn_s_setprio(0);
    if (i == nt - 1) {            // diagonal tile: mask key > q-row
#pragma unroll
      for (int c = 0; c < 4; c++)
#pragma unroll
        for (int r = 0; r < 4; r++) {
          int key = c * 16 + quad * 4 + r;       // block-relative
          if (key > wave * 16 + l16) s[c][r] = -1e30f;
        }
    }
#pragma unroll
    for (int c = 0; c < 4; c++)
#pragma unroll
      for (int r = 0; r < 4; r++)
        s[c][r] = __builtin_amdgcn_exp2f(s[c][r]);   // scores already log2-scaled
#pragma unroll
    for (int c = 0; c < 4; c++)
      lr += (s[c][0] + s[c][1]) + (s[c][2] + s[c][3]);
    // pack (f2bf manual) & write P[q=l16][key=c*16+quad*4..+3]
#pragma unroll
    for (int c = 0; c < 4; c++) {
      unsigned plo = (unsigned)f2bf(s[c][0]) | ((unsigned)f2bf(s[c][1]) << 16);
      unsigned phi = (unsigned)f2bf(s[c][2]) | ((unsigned)f2bf(s[c][3]) << 16);
      int ch = c * 2 + (quad >> 1);              // key>>3
      uint2 pk; pk.x = plo; pk.y = phi;
      *(uint2*)&P[l16 * 64 + ((ch ^ pxr) * 8) + (quad & 1) * 4] = pk;
    }
    __asm__ volatile("s_waitcnt lgkmcnt(0)" ::: "memory");
    short8 pa0 = *(const short8*)&P[l16 * 64 + ((quad ^ pxr) * 8)];
    short8 pa1 = *(const short8*)&P[l16 * 64 + (((quad + 4) ^ pxr) * 8)];
    __asm__ volatile("" ::: "memory");
    __builtin_amdgcn_s_setprio(1);
#pragma unroll
    for (int dt = 0; dt < 4; dt++) {
      O[dt] = MFMA(pa0, vf[dt][0], O[dt]);
      O[dt] = MFMA(pa1, vf[dt][1], O[dt]);
    }
    __builtin_amdgcn_s_setprio(0);
    __builtin_amdgcn_s_barrier();          // all waves done reading buf(i&1)
    __builtin_amdgcn_sched_barrier(0);
    if (i + 2 < nt) FSTAGE(i + 2, buf);    // overwrite just-consumed buffer
  }
#undef FSTAGE

  // row-sum: lane holds partial for q-row l16 over keys quad*4+r (mod 16)
  lr += __shfl_xor(lr, 16);
  lr += __shfl_xor(lr, 32);                // now full sum for q-row l16, all lanes

  int b = bh >> 4, h = bh & 15;
#pragma unroll
  for (int r = 0; r < 4; r++) {
    float inv = 1.0f / __shfl(lr, quad * 4 + r);   // sum for q-row quad*4+r
    size_t base = ((size_t)b * N_ + q0w + quad * 4 + r) * D_ + h * DH_;
#pragma unroll
    for (int dt = 0; dt < 4; dt++) sab[base + dt * 16 + l16] = f2bf(O[dt][r] * inv);
  }
}

// ------- output projection: 128x128 tile, BK=64, 8-wave, counted vmcnt ------
// (R8-proven) 2-deep prefetch, vmcnt(4) per K-step, chunk^(row&7) swizzle
// both-sides, setprio around MFMA cluster, XCD-mapped c0.
__global__ __launch_bounds__(512) void k_proj(const unsigned short* __restrict__ sab,
                                              const unsigned short* __restrict__ Wpb,
                                              const float* __restrict__ bproj,
                                              float* __restrict__ out) {
  __shared__ unsigned short LDSp[32768];   // 64 KiB: A[2][128][64] | B[2][128][64]
  const int t = threadIdx.x;
  const int wid = t >> 6, lane = t & 63, quad = lane >> 4, l16 = lane & 15;
  const int wr = wid >> 1, wc = wid & 1;          // 4 x 2 waves
  const int bid = blockIdx.x;
  const int m0 = (bid >> 3) * 128, c0 = (bid & 7) * 128;

  floatx4 acc[2][4];
#pragma unroll
  for (int i = 0; i < 2; i++)
#pragma unroll
    for (int j = 0; j < 4; j++) acc[i][j] = (floatx4){0.f, 0.f, 0.f, 0.f};

  const int slr = t >> 3;                          // 0..63
  const int sco = ((t & 7) ^ (slr & 7)) * 8;       // inverse-swizzled source
  const unsigned short* gA0 = sab + (size_t)(m0 +  0 + slr) * D_ + sco;
  const unsigned short* gA1 = sab + (size_t)(m0 + 64 + slr) * D_ + sco;
  const unsigned short* gB0 = Wpb + (size_t)(c0 +  0 + slr) * D_ + sco;
  const unsigned short* gB1 = Wpb + (size_t)(c0 + 64 + slr) * D_ + sco;
#define PA(gp, q, s, bb) GL_LDS16((gp) + (s) * 64, &LDSp[(bb) * 8192 + (q) * 4096 + t * 8])
#define PB(gp, q, s, bb) GL_LDS16((gp) + (s) * 64, &LDSp[16384 + (bb) * 8192 + (q) * 4096 + t * 8])

  const int aoff0 = ((quad)     ^ (l16 & 7)) * 8;  // k-chunk 0..3
  const int aoff1 = ((4 + quad) ^ (l16 & 7)) * 8;  // k-chunk 4..7
  const unsigned short* Abase = &LDSp[(wr * 32 + l16) * 64];
  const unsigned short* Bbase = &LDSp[16384 + (wc * 64 + l16) * 64];

  // prologue: tiles 0 and 1 (4 issues each)
  PA(gA0, 0, 0, 0); PA(gA1, 1, 0, 0); PB(gB0, 0, 0, 0); PB(gB1, 1, 0, 0);
  PA(gA0, 0, 1, 1); PA(gA1, 1, 1, 1); PB(gB0, 0, 1, 1); PB(gB1, 1, 1, 1);

  for (int i = 0; i < 16; i++) {
    const int buf = i & 1;
    const int so = buf * 8192;
    if (i + 1 < 16) { asm volatile("s_waitcnt vmcnt(4)" ::: "memory"); }
    else            { asm volatile("s_waitcnt vmcnt(0)" ::: "memory"); }
    __builtin_amdgcn_s_barrier();
    __builtin_amdgcn_sched_barrier(0);
    short8 a[2][2], b[4][2];
#pragma unroll
    for (int mi = 0; mi < 2; mi++) {
      a[mi][0] = *(const short8*)&Abase[so + mi * 1024 + aoff0];
      a[mi][1] = *(const short8*)&Abase[so + mi * 1024 + aoff1];
    }
#pragma unroll
    for (int ni = 0; ni < 4; ni++) {
      b[ni][0] = *(const short8*)&Bbase[so + ni * 1024 + aoff0];
      b[ni][1] = *(const short8*)&Bbase[so + ni * 1024 + aoff1];
    }
    __builtin_amdgcn_s_setprio(1);
#pragma unroll
    for (int mi = 0; mi < 2; mi++)
#pragma unroll
      for (int ni = 0; ni < 4; ni++) {
        acc[mi][ni] = MFMA(a[mi][0], b[ni][0], acc[mi][ni]);
        acc[mi][ni] = MFMA(a[mi][1], b[ni][1], acc[mi][ni]);
      }
    __builtin_amdgcn_s_setprio(0);
    __builtin_amdgcn_s_barrier();
    __builtin_amdgcn_sched_barrier(0);
    if (i + 2 < 16) {
      PA(gA0, 0, i + 2, buf); PA(gA1, 1, i + 2, buf);
      PB(gB0, 0, i + 2, buf); PB(gB1, 1, i + 2, buf);
    }
  }

#pragma unroll
  for (int mi = 0; mi < 2; mi++)
#pragma unroll
    for (int ni = 0; ni < 4; ni++) {
      int col = c0 + wc * 64 + ni * 16 + l16;
      int grow = m0 + wr * 32 + mi * 16 + quad * 4;
      float bias = bproj[col];
#pragma unroll
      for (int r = 0; r < 4; r++)
        out[(size_t)(grow + r) * D_ + col] = acc[mi][ni][r] + bias;
    }
#undef PA
#undef PB
}

extern "C" void kernel_launch(void* const* d_in, const int* in_sizes, int n_in,
                              void* d_out, int out_size, void* d_ws, size_t ws_size,
                              hipStream_t stream) {
  const float* x     = (const float*)d_in[0];
  const float* Wkqv  = (const float*)d_in[1];
  const float* bkqv  = (const float*)d_in[2];
  const float* Wproj = (const float*)d_in[3];
  const float* bproj = (const float*)d_in[4];
  float* out = (float*)d_out;

  char* w = (char*)d_ws;
  unsigned short* Xb  = (unsigned short*)(w);                       // 8 MiB  [B*N][D]
  unsigned short* Wt  = (unsigned short*)(w + (8u  << 20));         // 6 MiB  [3072][1024] (cat-permuted)
  unsigned short* Wpb = (unsigned short*)(w + (14u << 20));         // 2 MiB  [D][D]
  unsigned short* Qb  = (unsigned short*)(w + (16u << 20));         // 8 MiB  [B*H][N][DH] (pre-scaled by 0.125*log2e)
  unsigned short* Kb  = (unsigned short*)(w + (24u << 20));         // 8 MiB  [B*H][N][DH]
  unsigned short* Vt  = (unsigned short*)(w + (32u << 20));         // 8 MiB  [B*H][DH][N]
  unsigned short* sa  = (unsigned short*)(w + (40u << 20));         // 8 MiB  [B*N][D]

  k_prep<<<2048 + 768 + 512, 256, 0, stream>>>(x, Wkqv, Wproj, Xb, Wt, Wpb);
  k_qkv<<<dim3(B_ * N_ / 128, 3072 / 128), 256, 0, stream>>>(Xb, Wt, bkqv, Qb, Kb, Vt);
  k_flash<<<dim3(B_ * H_, N_ / 64), 256, 0, stream>>>(Qb, Kb, Vt, sa);
  k_proj<<<(B_ * N_ / 128) * (D_ / 128), 512, 0, stream>>>(sa, Wpb, bproj, out);
}